// Round 7
// baseline (441.065 us; speedup 1.0000x reference)
//
#include <hip/hip_runtime.h>

#define T_SEQ 512
#define HID 64
#define MB 16             // batch rows per block
#define NTHREADS 512      // 8 IDENTICAL waves: each 2 L1-tiles + 2 L2-tiles
// OPERAND-FLIPPED MFMA: A = weights (regs), B = h (LDS). D[gate-unit][batch].
// R17 RESTRUCTURE (merged-layer waves):
//   R15/R16 showed MFMA(475cy) + VALU(1060cy) are ADDITIVE per SIMD: lockstep
//   waves are always in the same phase, and an L1/L2-split wave has no MFMA
//   work independent of its own gates (R16's chain-pair reorder only bought
//   tail latency -> neutral). Merging L1+L2 into every wave creates a BULK
//   independent block: the 8 L2 MFMAs (~155cy matrix-pipe) execute under the
//   x-stage + L1-gate VALU block (~200cy), pinned by sched_barrier(0).
//   Also: all waves now carry identical load (no L1/L2 barrier skew), no
//   isL1 divergence. Cost: 40 b128 reads/step vs 28 (conflicts ~x1.4).
// R14 lesson: packed-f32 gates serialized the gate chains -> scalar gates,
//   4 independent chains per thread (ILP=4) kept here.
// R12 lesson: x-in-regs + setprio regressed; cvt_pk + merged-rcp gate = real.
// UNIT PERMUTATION: LDS position p holds unit U(p) = (p&~7)+((p&7)>>1)+((p&1)<<2)
// -> thread (wave,quad) owns units {8w+quad, 8w+quad+4}: one packed b32
//    h-store per layer at hpos = 8w+2*quad.
// Strides: 104 shorts = 52 dw == 20 mod 32 -> 2-way max read aliasing (benign).
#define A1STR 104
#define A2STR 104

typedef __attribute__((ext_vector_type(8))) short short8;
typedef __attribute__((ext_vector_type(4))) float floatx4;

#define LOG2E 1.4426950408889634f

__device__ __forceinline__ short f2bf_rne(float v) {
  unsigned u = __float_as_uint(v);
  return (short)((u + 0x7FFFu + ((u >> 16) & 1u)) >> 16);
}
__device__ __forceinline__ float rcp_(float x) { return __builtin_amdgcn_rcpf(x); }
__device__ __forceinline__ float exp2_(float x) { return __builtin_amdgcn_exp2f(x); }

// one-instruction RNE pack of two f32 -> 2x bf16 (no builtin on gfx950)
__device__ __forceinline__ unsigned cvt_pk_bf16(float lo, float hi) {
  unsigned r;
  asm("v_cvt_pk_bf16_f32 %0, %1, %2" : "=v"(r) : "v"(lo), "v"(hi));
  return r;
}

// Hot-loop barrier: LDS-publish only (drops the vmcnt(0)/expcnt(0) drain that
// __syncthreads forces; only this-wave x loads are in flight, waited at use).
__device__ __forceinline__ void barrier_lds() {
  asm volatile("s_waitcnt lgkmcnt(0)" ::: "memory");
  __builtin_amdgcn_s_barrier();
  asm volatile("" ::: "memory");
}

// Scalar gates (R3-verified; R14 showed packing the chains hurts latency).
// gates pre-scaled: p[0,1,3] by LOG2E, p[2] by 2*LOG2E. rcp-fused, f-rcp and
// ig-rcp merged (7 trans):
//   t1 = (1+A)(G+1); t2 = (1+F)
//   c  = (c*t1 + (G-1)*t2) * rcp(t1*t2)
//   h  = (C-1) * rcp((1+O)(C+1)),  C = exp2(2*log2e*c)
__device__ __forceinline__ float gate_h(const floatx4 p, float& c) {
  float A = exp2_(-p[0]);
  float F = exp2_(-p[1]);
  float G = exp2_(p[2]);
  float O = exp2_(-p[3]);
  float t1 = (1.f + A) * (G + 1.f);
  float t2 = 1.f + F;
  float num = c * t1 + (G - 1.f) * t2;
  c = num * rcp_(t1 * t2);
  float C = exp2_((2.f * LOG2E) * c);
  return (C - 1.f) * rcp_((1.f + O) * (C + 1.f));
}

// unit stored at LDS h-position p
__device__ __forceinline__ int uofp(int p) {
  return (p & ~7) + ((p & 7) >> 1) + ((p & 1) << 2);
}

// Layer-1 weight at A-frag k-slot (K1=96): k<64 pairs h1 positions, 64..70 x
__device__ __forceinline__ short w1elem(int k, int n, float wsc,
                                        const float* __restrict__ Wih0,
                                        const float* __restrict__ Whh0) {
  float v;
  if      (k < 64) { v = Whh0[n*64 + uofp(k)]; }
  else if (k < 71) { v = Wih0[n*7 + (k - 64)]; }
  else return (short)0;
  return f2bf_rne(v * wsc);
}
// Layer-2 weight (K2=128): k<64 pairs h1 positions, 64..127 pairs h2 positions
__device__ __forceinline__ short w2elem(int k, int n, float wsc,
                                        const float* __restrict__ Wih1,
                                        const float* __restrict__ Whh1) {
  float v;
  if (k < 64) { v = Wih1[n*64 + uofp(k)]; }
  else        { v = Whh1[n*64 + uofp(k - 64)]; }
  return f2bf_rne(v * wsc);
}

// A = weights (first arg), B = h (second arg)
#define MFMA(A, B, C) __builtin_amdgcn_mfma_f32_16x16x32_bf16((A), (B), (C), 0, 0, 0)

__global__ __launch_bounds__(NTHREADS, 2) void lstm_fused(
    const float* __restrict__ x,
    const float* __restrict__ Wih0, const float* __restrict__ Whh0,
    const float* __restrict__ bih0, const float* __restrict__ bhh0,
    const float* __restrict__ Wih1, const float* __restrict__ Whh1,
    const float* __restrict__ bih1, const float* __restrict__ bhh1,
    const float* __restrict__ Wfc,  const float* __restrict__ bfc,
    float* __restrict__ out)
{
  __shared__ __align__(16) short A1[2][MB][A1STR];
  __shared__ __align__(16) short A2[2][MB][A2STR];
  __shared__ float h2f[MB][HID + 4];

  const int tid  = threadIdx.x;
  const int lane = tid & 63;
  const int wave = tid >> 6;           // 0..7 (all identical roles)
  const int l15  = lane & 15;          // batch column / A-frag row
  const int quad = lane >> 4;
  const int quad8= quad * 8;
  const int g4   = l15 & 3;
  const int b0   = blockIdx.x * MB;
  const int ua   = wave*8 + quad;      // owned units (both layers): ua, ua+4
  const int hpos = wave*8 + 2*quad;    // packed h position (shorts, even)
  const int na   = g4*64 + wave*8 + (l15 >> 2);   // tile-a weight row
  const int nb   = na + 4;                        // tile-b weight row
  const float wsc = (g4 == 2) ? 2.f * LOG2E : LOG2E;

  // ---- zero both staging buffers (h(-1) = 0, x pad = 0) ----
  for (int i = tid; i < 2*MB*A1STR/2; i += NTHREADS) ((unsigned*)A1)[i] = 0u;
  for (int i = tid; i < 2*MB*A2STR/2; i += NTHREADS) ((unsigned*)A2)[i] = 0u;
  __syncthreads();   // zeroing fully done before anyone stages x into A1[0]

  // ---- biases for owned units, BOTH layers ----
  floatx4 b1a, b1b, b2a, b2b;
  #pragma unroll
  for (int g = 0; g < 4; ++g) {
    float ws = (g == 2) ? 2.f * LOG2E : LOG2E;
    b1a[g] = (bih0[g*64 + ua    ] + bhh0[g*64 + ua    ]) * ws;
    b1b[g] = (bih0[g*64 + ua + 4] + bhh0[g*64 + ua + 4]) * ws;
    b2a[g] = (bih1[g*64 + ua    ] + bhh1[g*64 + ua    ]) * ws;
    b2b[g] = (bih1[g*64 + ua + 4] + bhh1[g*64 + ua + 4]) * ws;
  }

  // ---- x staging: 8 waves x 2 rows each (row = 2*wave + lane>>5).
  // Pair-packed: lane xd2 in 0..3 owns x elements {2*xd2, 2*xd2+1} of its
  // row (element 7 is the zero pad; x[7] never touched -> no OOB). One
  // cvt_pk + one b32 LDS write per lane; prefetch distance = one full step.
  const int xd2  = lane & 31;          // 0..3 active
  const int xrow = 2*wave + (lane >> 5);
  const bool xact = (xd2 < 4);
  const float* xbase = x + ((size_t)(b0 + xrow) * T_SEQ) * 7 + 2*xd2;
  float xc0 = 0.f, xc1 = 0.f;
  if (xact) {
    *(unsigned*)&A1[0][xrow][64 + 2*xd2] =
        cvt_pk_bf16(xbase[0], (xd2 < 3) ? xbase[1] : 0.f);
    xc0 = xbase[7];
    xc1 = (xd2 < 3) ? xbase[8] : 0.f;
  }

  // ---- weight A-fragments: 2 L1 tiles + 2 L2 tiles per wave ----
  short8 W1a[3], W1b[3], W2a[4], W2b[4];
  #pragma unroll
  for (int ks = 0; ks < 3; ++ks) {
    short8 fa, fb;
    #pragma unroll
    for (int jj = 0; jj < 8; ++jj) {
      fa[jj] = w1elem(ks*32 + quad8 + jj, na, wsc, Wih0, Whh0);
      fb[jj] = w1elem(ks*32 + quad8 + jj, nb, wsc, Wih0, Whh0);
    }
    W1a[ks] = fa; W1b[ks] = fb;
  }
  #pragma unroll
  for (int ks = 0; ks < 4; ++ks) {
    short8 fa, fb;
    #pragma unroll
    for (int jj = 0; jj < 8; ++jj) {
      fa[jj] = w2elem(ks*32 + quad8 + jj, na, wsc, Wih1, Whh1);
      fb[jj] = w2elem(ks*32 + quad8 + jj, nb, wsc, Wih1, Whh1);
    }
    W2a[ks] = fa; W2b[ks] = fb;
  }
  __syncthreads();

  float c1a = 0.f, c1b = 0.f, c2a = 0.f, c2b = 0.f;   // c-state, 4 owned units

#define STEP_X(NXT, XT)                                                      \
    if (xact) {                                                              \
      *(unsigned*)&A1[NXT][xrow][64 + 2*xd2] = cvt_pk_bf16(xc0, xc1);        \
      xc0 = xbase[7 * (XT)];                                                 \
      xc1 = (xd2 < 3) ? xbase[7 * (XT) + 1] : 0.f;                           \
    }

// Full merged step: reads -> ALL MFMA issues -> sched_barrier(0) pin ->
// x-stage + L1 gates + h1 write + L2 gates + h2 write. The 8 L2 MFMAs
// execute in the matrix pipe underneath the x-stage/L1-gate VALU block.
#define STEP_FULL(CUR, NXT, IT)                                              \
  {                                                                          \
    short8 hf0 = *(const short8*)&A1[CUR][l15][     quad8];                  \
    short8 hf1 = *(const short8*)&A1[CUR][l15][32 + quad8];                  \
    short8 hfx = *(const short8*)&A1[CUR][l15][64 + quad8];                  \
    short8 h20 = *(const short8*)&A2[CUR][l15][     quad8];                  \
    short8 h21 = *(const short8*)&A2[CUR][l15][32 + quad8];                  \
    floatx4 p1a = MFMA(W1a[0], hf0, b1a);                                    \
    floatx4 p1b = MFMA(W1b[0], hf0, b1b);                                    \
    p1a = MFMA(W1a[1], hf1, p1a);  p1b = MFMA(W1b[1], hf1, p1b);             \
    p1a = MFMA(W1a[2], hfx, p1a);  p1b = MFMA(W1b[2], hfx, p1b);             \
    floatx4 p2a = MFMA(W2a[0], hf0, b2a);                                    \
    floatx4 p2b = MFMA(W2b[0], hf0, b2b);                                    \
    p2a = MFMA(W2a[1], hf1, p2a);  p2b = MFMA(W2b[1], hf1, p2b);             \
    p2a = MFMA(W2a[2], h20, p2a);  p2b = MFMA(W2b[2], h20, p2b);             \
    p2a = MFMA(W2a[3], h21, p2a);  p2b = MFMA(W2b[3], h21, p2b);             \
    __builtin_amdgcn_sched_barrier(0);                                       \
    int xt_ = (IT) + 2; if (xt_ > T_SEQ - 1) xt_ = T_SEQ - 1;                \
    STEP_X(NXT, xt_)                                                         \
    float h1a = gate_h(p1a, c1a);                                            \
    float h1b = gate_h(p1b, c1b);                                            \
    *(unsigned*)&A1[NXT][l15][hpos] = cvt_pk_bf16(h1a, h1b);                 \
    float h2a = gate_h(p2a, c2a);                                            \
    float h2b = gate_h(p2b, c2b);                                            \
    *(unsigned*)&A2[NXT][l15][hpos] = cvt_pk_bf16(h2a, h2b);                 \
    barrier_lds();                                                           \
  }

  // ---- it = 0: L1 half only (A2[1] keeps zeros = h2(-1)) ----
  {
    short8 hf0 = *(const short8*)&A1[0][l15][     quad8];
    short8 hf1 = *(const short8*)&A1[0][l15][32 + quad8];
    short8 hfx = *(const short8*)&A1[0][l15][64 + quad8];
    floatx4 p1a = MFMA(W1a[0], hf0, b1a);
    floatx4 p1b = MFMA(W1b[0], hf0, b1b);
    p1a = MFMA(W1a[1], hf1, p1a);  p1b = MFMA(W1b[1], hf1, p1b);
    p1a = MFMA(W1a[2], hfx, p1a);  p1b = MFMA(W1b[2], hfx, p1b);
    STEP_X(1, 2)
    float h1a = gate_h(p1a, c1a);
    float h1b = gate_h(p1b, c1b);
    *(unsigned*)&A1[1][l15][hpos] = cvt_pk_bf16(h1a, h1b);
    barrier_lds();
  }

  // ---- main: it = 1..510, two steps per trip ----
  #pragma unroll 1
  for (int k = 0; k < 255; ++k) {
    STEP_FULL(1, 0, 2*k + 1)
    STEP_FULL(0, 1, 2*k + 2)
  }
  // ---- it = 511 ----
  STEP_FULL(1, 0, 511)

  // ---- it = 512: L2 half only; write final h2 as f32 (natural unit idx) ----
  {
    short8 hf0 = *(const short8*)&A1[0][l15][     quad8];
    short8 hf1 = *(const short8*)&A1[0][l15][32 + quad8];
    short8 h20 = *(const short8*)&A2[0][l15][     quad8];
    short8 h21 = *(const short8*)&A2[0][l15][32 + quad8];
    floatx4 p2a = MFMA(W2a[0], hf0, b2a);
    floatx4 p2b = MFMA(W2b[0], hf0, b2b);
    p2a = MFMA(W2a[1], hf1, p2a);  p2b = MFMA(W2b[1], hf1, p2b);
    p2a = MFMA(W2a[2], h20, p2a);  p2b = MFMA(W2b[2], h20, p2b);
    p2a = MFMA(W2a[3], h21, p2a);  p2b = MFMA(W2b[3], h21, p2b);
    h2f[l15][ua    ] = gate_h(p2a, c2a);
    h2f[l15][ua + 4] = gate_h(p2b, c2b);
    __syncthreads();
  }

  // ---- final FC ----
  if (tid < MB * 4) {
    int bbf = tid >> 2, o = tid & 3;
    float acc = bfc[o];
    #pragma unroll 8
    for (int kk = 0; kk < HID; ++kk) acc += h2f[bbf][kk] * Wfc[o*HID + kk];
    out[(size_t)(b0 + bbf) * 4 + o] = acc;
  }
}

extern "C" void kernel_launch(void* const* d_in, const int* in_sizes, int n_in,
                              void* d_out, int out_size, void* d_ws, size_t ws_size,
                              hipStream_t stream) {
  const float* x    = (const float*)d_in[0];
  const float* Wih0 = (const float*)d_in[1];
  const float* Whh0 = (const float*)d_in[2];
  const float* bih0 = (const float*)d_in[3];
  const float* bhh0 = (const float*)d_in[4];
  const float* Wih1 = (const float*)d_in[5];
  const float* Whh1 = (const float*)d_in[6];
  const float* bih1 = (const float*)d_in[7];
  const float* bhh1 = (const float*)d_in[8];
  const float* Wfc  = (const float*)d_in[9];
  const float* bfc  = (const float*)d_in[10];
  (void)d_ws; (void)ws_size; (void)n_in; (void)out_size;

  const int B = in_sizes[0] / (T_SEQ * 7);   // 4096
  dim3 grid(B / MB);
  lstm_fused<<<grid, NTHREADS, 0, stream>>>(x, Wih0, Whh0, bih0, bhh0,
                                            Wih1, Whh1, bih1, bhh1, Wfc, bfc,
                                            (float*)d_out);
}